// Round 3
// baseline (11.283 us; speedup 1.0000x reference)
//
#include <hip/hip_runtime.h>
#include <hip/hip_bf16.h>

#define EOS_TOKEN 1
#define B 8
#define T 1024
#define V 32000

// Single block, 1024 threads. Thread t handles position t of every sequence.
// Gathers are issued unconditionally right after target loads so the EOS
// reduction (atomicMin in LDS) overlaps gather latency instead of preceding it.
__global__ void seq_nll_fused_kernel(const float* __restrict__ inp,
                                     const int* __restrict__ tgt,
                                     float* __restrict__ out) {
    const int t = threadIdx.x;

    __shared__ int s_eos[B];
    if (t < B) s_eos[t] = T;  // sentinel; setup guarantees one EOS per row
    __syncthreads();

    // 1) load targets (independent, coalesced) and immediately issue all
    //    gathers (dependent only on tg, NOT on eos)
    int tg[B];
    #pragma unroll
    for (int b = 0; b < B; ++b) tg[b] = tgt[b * T + t];

    float v[B];
    #pragma unroll
    for (int b = 0; b < B; ++b) {
        v[b] = inp[(size_t)b * T * V + (size_t)t * V + (size_t)tg[b]];
    }

    // 2) EOS find runs concurrently with gather latency
    #pragma unroll
    for (int b = 0; b < B; ++b) {
        if (tg[b] == EOS_TOKEN) atomicMin(&s_eos[b], t);
    }
    __syncthreads();

    // 3) mask + scale + accumulate
    float acc = 0.0f;
    #pragma unroll
    for (int b = 0; b < B; ++b) {
        const int eos = s_eos[b];
        if (t <= eos) acc += -v[b] / (float)eos;  // reference divides by eos_idx
    }

    // 4) wave (64-lane) shuffle reduction
    #pragma unroll
    for (int off = 32; off > 0; off >>= 1) {
        acc += __shfl_down(acc, off);
    }

    __shared__ float s_wsum[16];  // 1024 / 64 = 16 waves
    const int wave = t >> 6;
    const int lane = t & 63;
    if (lane == 0) s_wsum[wave] = acc;
    __syncthreads();

    // 5) wave 0 reduces the 16 partials via shuffle (shallower than serial loop)
    if (wave == 0) {
        float s = (lane < 16) ? s_wsum[lane] : 0.0f;
        #pragma unroll
        for (int off = 8; off > 0; off >>= 1) {
            s += __shfl_down(s, off);
        }
        if (lane == 0) out[0] = s;
    }
}

extern "C" void kernel_launch(void* const* d_in, const int* in_sizes, int n_in,
                              void* d_out, int out_size, void* d_ws, size_t ws_size,
                              hipStream_t stream) {
    const float* inp = (const float*)d_in[0];   // [B, T, V] float32 log-probs
    const int* tgt = (const int*)d_in[1];       // [B, T] int32
    float* out = (float*)d_out;                 // scalar float32

    seq_nll_fused_kernel<<<1, T, 0, stream>>>(inp, tgt, out);
}

// Round 4
// 10.376 us; speedup vs baseline: 1.0874x; 1.0874x over previous
//
#include <hip/hip_runtime.h>
#include <hip/hip_bf16.h>

#define EOS_TOKEN 1
#define B 8
#define T 1024
#define V 32000

// Single block, 1024 threads. Thread t handles position t of every sequence.
// Total loss re-associated as sum over (b,t) of mask * (-logp)/eos_idx[b],
// reduced block-wide in one pass -> one kernel launch, deterministic.
// This is the Round-2 variant: best measured (10.36 us), simplest structure.
// The op is launch-overhead bound; kernel-side work is ~1-2 us.
__global__ void seq_nll_fused_kernel(const float* __restrict__ inp,
                                     const int* __restrict__ tgt,
                                     float* __restrict__ out) {
    const int t = threadIdx.x;

    __shared__ int s_eos[B];
    if (t < B) s_eos[t] = T;  // sentinel; setup guarantees one EOS per row
    __syncthreads();

    // load targets for all sequences at this position; find first EOS per row
    int tg[B];
    #pragma unroll
    for (int b = 0; b < B; ++b) {
        tg[b] = tgt[b * T + t];
        if (tg[b] == EOS_TOKEN) atomicMin(&s_eos[b], t);
    }
    __syncthreads();

    // gather + scale; 8 independent loads per thread for latency hiding
    float acc = 0.0f;
    #pragma unroll
    for (int b = 0; b < B; ++b) {
        const int eos = s_eos[b];
        if (t <= eos) {
            const float v = inp[(size_t)b * T * V + (size_t)t * V + (size_t)tg[b]];
            acc += -v / (float)eos;   // reference divides by eos_idx (not +1)
        }
    }

    // wave (64-lane) shuffle reduction
    #pragma unroll
    for (int off = 32; off > 0; off >>= 1) {
        acc += __shfl_down(acc, off);
    }

    __shared__ float s_wsum[16];  // 1024 / 64 = 16 waves
    const int wave = t >> 6;
    const int lane = t & 63;
    if (lane == 0) s_wsum[wave] = acc;
    __syncthreads();

    if (t == 0) {
        float s = 0.0f;
        #pragma unroll
        for (int w = 0; w < 16; ++w) s += s_wsum[w];
        out[0] = s;
    }
}

extern "C" void kernel_launch(void* const* d_in, const int* in_sizes, int n_in,
                              void* d_out, int out_size, void* d_ws, size_t ws_size,
                              hipStream_t stream) {
    const float* inp = (const float*)d_in[0];   // [B, T, V] float32 log-probs
    const int* tgt = (const int*)d_in[1];       // [B, T] int32
    float* out = (float*)d_out;                 // scalar float32

    seq_nll_fused_kernel<<<1, T, 0, stream>>>(inp, tgt, out);
}